// Round 10
// baseline (486.988 us; speedup 1.0000x reference)
//
#include <hip/hip_runtime.h>
#include <hip/hip_bf16.h>

// Problem constants (SymNetDP): B=64, S=4096, NGB=13, NG=48, DIM=3, NCH={8,8,1}
#define BATCH 64
#define SITES 4096
#define NGB 13
#define NGRP 48
#define SDIM 3

typedef __bf16 bf16x8 __attribute__((ext_vector_type(8)));
typedef float  f32x4  __attribute__((ext_vector_type(4)));

// ---------------------------------------------------------------------------
// Workspace layout (floats):
//   Avc  : 39 f32 (pad 64)              @ 0
//   U    : bf16 x 135168 (67584 f)      @ 64
//     W0H [384][32] | W0L | W1H [384][128] | W1L | W2H [48][128] | W2L
//   Ah0/Al0 : (B,S,8) bf16 = 1048576 f each  @ 67648 / 1116224
//   Ah1/Al1 : (B,S,8) bf16                   @ 2164800 / 3213376
//   A2   : (B,S) f32, aliases Ah0 (dead when L2 runs)  @ 67648
//   PART : (64,16,3)                     @ 4261952
// K-packing (NCIN=8): k = j*8 + c  (a site's 8 channels contiguous).
// ---------------------------------------------------------------------------
#define OFF_AVC  0
#define OFF_U    64
#define OFF_AH0  67648
#define OFF_AL0  1116224
#define OFF_AH1  2164800
#define OFF_AL1  3213376
#define OFF_A2   67648
#define OFF_PART 4261952
#define UW0H 0
#define UW0L 12288
#define UW1H 24576
#define UW1L 73728
#define UW2H 122880
#define UW2L 129024

__device__ __forceinline__ float softplus_f(float h) {
    return fmaxf(h, 0.f) + __logf(1.f + __expf(-fabsf(h)));
}

// ---------------------------------------------------------------------------
// Precompute: rotated weights, bf16 hi/lo split, [row=o*48+g][KPAD] with
// k = j*8+c packing for K=104 layers (k = j for layer 0); plus Avc.
// ---------------------------------------------------------------------------
__global__ __launch_bounds__(256) void precompute_kernel(
    const float* __restrict__ Psi0, const float* __restrict__ Psi1,
    const float* __restrict__ Psi2, const float* __restrict__ wtVC,
    const float* __restrict__ gdiags, const int* __restrict__ perms,
    float* __restrict__ ws)
{
    float*  Avc = ws + OFF_AVC;
    __bf16* U   = (__bf16*)(ws + OFF_U);
    int t = blockIdx.x * 256 + threadIdx.x;
    if (t < 12288) {                       // W0: [384][32], k=j
        int k = t & 31, row = t >> 5;
        int o = row / NGRP, g = row - o * NGRP;
        float w = (k < NGB) ? Psi0[o * NGB + perms[g * NGB + k]] : 0.f;
        __bf16 hi = (__bf16)w;
        U[UW0H + t] = hi;
        U[UW0L + t] = (__bf16)(w - (float)hi);
    } else if (t < 61440) {                // W1: [384][128], k=j*8+c
        int u = t - 12288;
        int k = u & 127, row = u >> 7;
        int o = row / NGRP, g = row - o * NGRP;
        float w = 0.f;
        if (k < 104) { int j = k >> 3, c = k & 7;
                       w = Psi1[(o * 8 + c) * NGB + perms[g * NGB + j]]; }
        __bf16 hi = (__bf16)w;
        U[UW1H + u] = hi;
        U[UW1L + u] = (__bf16)(w - (float)hi);
    } else if (t < 67584) {                // W2: [48][128], k=j*8+c
        int u = t - 61440;
        int k = u & 127, g = u >> 7;
        float w = 0.f;
        if (k < 104) { int j = k >> 3, c = k & 7;
                       w = Psi2[c * NGB + perms[g * NGB + j]]; }
        __bf16 hi = (__bf16)w;
        U[UW2H + u] = hi;
        U[UW2L + u] = (__bf16)(w - (float)hi);
    } else if (t < 67584 + 39 * NGRP) {    // Avc
        int t2 = t - 67584;
        int g = t2 % NGRP, u = t2 / NGRP;
        int d = u / NGB, n = u % NGB;
        const int row = g * SDIM + d;
        float s = 0.f;
        for (int k = 0; k < NGRP * SDIM; k++) {
            int g2 = k / SDIM, d2 = k - g2 * SDIM;
            float p = wtVC[d2 * NGB + perms[g2 * NGB + n]];
            s = fmaf(gdiags[row * (NGRP * SDIM) + k], p, s);
        }
        atomicAdd(&Avc[u], s * (1.f / 48.f));
    }
}

// ---------------------------------------------------------------------------
// Pipelined MFMA gconv layer (bf16x3 split), v10.
// Block processes P consecutive CT-column chunks. Single LDS buffer (34.8 KB
// -> 4 blocks/CU); pipeline via REGISTERS: gathers for chunk p+1 issue before
// compute(p) (latency hidden by MFMA+epilogue), committed to LDS between two
// barriers at the top of the next iteration.
// Producers write pre-split Ah/Al (SOUT=1) -> staging here is pure b128 copy.
// ---------------------------------------------------------------------------
template<int NCIN, int NCTOT, int CT, int KPAD, int KSTR, int NWAVES, int NWN,
         int P, int SOUT>
__global__ __launch_bounds__(NWAVES * 64, 4) void layer_pipe(
    const float*  __restrict__ prevF,   // NCIN==1 source (f32)
    const __bf16* __restrict__ prevH,   // NCIN==8 pre-split hi (B,S,8)
    const __bf16* __restrict__ prevL,   //            ... lo
    const __bf16* __restrict__ Wh,      // [NCTOT*48][KPAD]
    const __bf16* __restrict__ Wl,
    const float*  __restrict__ bias,    // (NCTOT,)
    const int*    __restrict__ NN,      // (13, S)
    float*  __restrict__ outF,          // SOUT==0: (B,S) f32
    __bf16* __restrict__ outH,          // SOUT==1: (B,S,NCTOT) bf16 hi
    __bf16* __restrict__ outL)          //            ... lo
{
    constexpr int NTHR   = NWAVES * 64;
    constexpr int K      = NCIN * NGB;
    constexpr int M      = NCTOT * NGRP;
    constexpr int MTILES = M / 16, NTILES = CT / 16;
    constexpr int NWM    = NWAVES / NWN;
    constexpr int MT_W   = MTILES / NWM, NT_W = NTILES / NWN;
    constexpr int KT     = KPAD / 32;
    constexpr int NSITE  = NGB * CT;
    constexpr int NSL    = (NSITE + NTHR - 1) / NTHR;

    static_assert(MT_W * 16 == NGRP, "wave covers exactly one o");
    static_assert(NWM * MT_W == MTILES && NWN * NT_W == NTILES, "");
    static_assert((KPAD & 31) == 0 && (KSTR & 7) == 0, "");
    static_assert((SITES / CT) % P == 0, "");

    __shared__ __align__(16) __bf16 xh_lds[CT * KSTR];
    __shared__ __align__(16) __bf16 xl_lds[CT * KSTR];

    const int tid  = threadIdx.x;
    const int wave = tid >> 6, lane = tid & 63;
    const int m16  = lane & 15, quad = lane >> 4;

    constexpr int QPB = (SITES / CT) / P;
    const int b     = blockIdx.x / QPB;
    const int qq    = blockIdx.x % QPB;
    const int sbase = qq * (P * CT);
    const size_t bS = (size_t)b * SITES;

    const int wave_mt0 = (wave / NWN) * MT_W;
    const int wave_nt0 = (wave % NWN) * NT_W;
    const int o_g      = (wave_mt0 * 16) / NGRP;
    const float bo     = bias[o_g];

    // --- zero-pad k in [K, KPAD) once (staging never touches it) ------------
    if constexpr (NCIN == 8) {
        const bf16x8 z8 = {};
        for (int e = tid; e < CT * 3; e += NTHR) {
            int col = e % CT, z = e / CT;
            *(bf16x8*)(xh_lds + col * KSTR + K + z * 8) = z8;
            *(bf16x8*)(xl_lds + col * KSTR + K + z * 8) = z8;
        }
    } else {
        for (int e = tid; e < CT * (KPAD - K); e += NTHR) {
            int col = e % CT, z = e / CT;
            xh_lds[col * KSTR + K + z] = (__bf16)0.f;
            xl_lds[col * KSTR + K + z] = (__bf16)0.f;
        }
    }

    // --- register staging state ---------------------------------------------
    bf16x8 hreg[NSL], lreg[NSL];
    float  vreg[NSL];

    auto gather = [&](int pp) {
        const int s0_ = sbase + pp * CT;
#pragma unroll
        for (int i = 0; i < NSL; i++) {
            int site = tid + i * NTHR;
            if (site < NSITE) {
                int j = site / CT, col = site % CT;
                int nn = NN[j * SITES + s0_ + col];
                if constexpr (NCIN == 1) {
                    vreg[i] = prevF[bS + nn];
                } else {
                    size_t a8 = (bS + nn) * 8;
                    hreg[i] = *(const bf16x8*)(prevH + a8);
                    lreg[i] = *(const bf16x8*)(prevL + a8);
                }
            }
        }
    };

    auto commit = [&]() {
#pragma unroll
        for (int i = 0; i < NSL; i++) {
            int site = tid + i * NTHR;
            if (site < NSITE) {
                int j = site / CT, col = site % CT;
                if constexpr (NCIN == 1) {
                    int la = col * KSTR + j;
                    __bf16 hi = (__bf16)vreg[i];
                    xh_lds[la] = hi;
                    xl_lds[la] = (__bf16)(vreg[i] - (float)hi);
                } else {
                    int la = col * KSTR + j * 8;
                    *(bf16x8*)(xh_lds + la) = hreg[i];
                    *(bf16x8*)(xl_lds + la) = lreg[i];
                }
            }
        }
    };

    gather(0);

#pragma unroll 1
    for (int p = 0; p < P; p++) {
        __syncthreads();            // prior chunk's LDS reads complete
        commit();                   // regs -> LDS
        __syncthreads();
        if (p + 1 < P) gather(p + 1);   // issue next gathers early (VMEM)

        const int s0_ = sbase + p * CT;
        f32x4 acc[MT_W][NT_W];
#pragma unroll
        for (int mt = 0; mt < MT_W; mt++)
#pragma unroll
            for (int nt = 0; nt < NT_W; nt++)
                acc[mt][nt] = (f32x4){0.f, 0.f, 0.f, 0.f};

        // K loop: hi*hi + lo*hi + hi*lo per (tile, k32)
#pragma unroll
        for (int kt = 0; kt < KT; kt++) {
            const int koff = kt * 32 + quad * 8;
            bf16x8 ah[MT_W], al[MT_W], bh[NT_W], bl[NT_W];
#pragma unroll
            for (int mt = 0; mt < MT_W; mt++) {
                int row = (wave_mt0 + mt) * 16 + m16;
                ah[mt] = *(const bf16x8*)(Wh + (size_t)row * KPAD + koff);
                al[mt] = *(const bf16x8*)(Wl + (size_t)row * KPAD + koff);
            }
#pragma unroll
            for (int nt = 0; nt < NT_W; nt++) {
                int cb = ((wave_nt0 + nt) * 16 + m16) * KSTR + koff;
                bh[nt] = *(const bf16x8*)(xh_lds + cb);
                bl[nt] = *(const bf16x8*)(xl_lds + cb);
            }
#pragma unroll
            for (int mt = 0; mt < MT_W; mt++)
#pragma unroll
                for (int nt = 0; nt < NT_W; nt++) {
                    acc[mt][nt] = __builtin_amdgcn_mfma_f32_16x16x32_bf16(
                        ah[mt], bh[nt], acc[mt][nt], 0, 0, 0);
                    acc[mt][nt] = __builtin_amdgcn_mfma_f32_16x16x32_bf16(
                        al[mt], bh[nt], acc[mt][nt], 0, 0, 0);
                    acc[mt][nt] = __builtin_amdgcn_mfma_f32_16x16x32_bf16(
                        ah[mt], bl[nt], acc[mt][nt], 0, 0, 0);
                }
        }

        // epilogue: softplus + group mean (one o per wave)
#pragma unroll
        for (int nt = 0; nt < NT_W; nt++) {
            float s = 0.f;
#pragma unroll
            for (int mt = 0; mt < MT_W; mt++)
#pragma unroll
                for (int r = 0; r < 4; r++)
                    s += softplus_f(acc[mt][nt][r] + bo);
            s += __shfl_xor(s, 16);
            s += __shfl_xor(s, 32);
            if (quad == 0) {
                int site = s0_ + (wave_nt0 + nt) * 16 + m16;
                float val = s * (1.f / 48.f);
                if constexpr (SOUT) {
                    size_t idx = (bS + site) * NCTOT + o_g;
                    __bf16 hi = (__bf16)val;
                    outH[idx] = hi;
                    outL[idx] = (__bf16)(val - (float)hi);
                } else {
                    outF[bS + site] = val;
                }
            }
        }
    }
}

// ---------------------------------------------------------------------------
// Reduce stage A: per (b, s-chunk) block -> 3 partial sums
// ---------------------------------------------------------------------------
__global__ __launch_bounds__(256) void reduce_a(
    const float* __restrict__ A2, const int* __restrict__ NN,
    const int* __restrict__ s2sh, const float* __restrict__ sw,
    const float* __restrict__ Avc, float* __restrict__ partial)
{
    const int b = blockIdx.x >> 4;
    const int chunk = blockIdx.x & 15;
    const int tid = threadIdx.x;
    const int s = (chunk << 8) + tid;
    const float* a = A2 + (size_t)b * SITES;

    float y0 = 0.f, y1 = 0.f, y2 = 0.f;
#pragma unroll
    for (int n = 0; n < NGB; n++) {
        float v = a[NN[n * SITES + s]];
        y0 = fmaf(Avc[n],           v, y0);
        y1 = fmaf(Avc[NGB + n],     v, y1);
        y2 = fmaf(Avc[2 * NGB + n], v, y2);
    }
    const float wgt = sw[s2sh[s]];
    y0 *= wgt; y1 *= wgt; y2 *= wgt;

    __shared__ float red[3][256];
    red[0][tid] = y0; red[1][tid] = y1; red[2][tid] = y2;
    __syncthreads();
    for (int st = 128; st > 0; st >>= 1) {
        if (tid < st) {
            red[0][tid] += red[0][tid + st];
            red[1][tid] += red[1][tid + st];
            red[2][tid] += red[2][tid + st];
        }
        __syncthreads();
    }
    if (tid < 3) partial[(b * 16 + chunk) * 3 + tid] = red[tid][0];
}

__global__ __launch_bounds__(256) void reduce_b(
    const float* __restrict__ partial, float* __restrict__ out)
{
    int t = threadIdx.x;
    if (t < BATCH * 3) {
        int b = t / 3, d = t - b * 3;
        float s = 0.f;
        for (int c = 0; c < 16; c++) s += partial[(b * 16 + c) * 3 + d];
        out[t] = s * (1.f / (float)SITES);
    }
}

// ---------------------------------------------------------------------------
extern "C" void kernel_launch(void* const* d_in, const int* in_sizes, int n_in,
                              void* d_out, int out_size, void* d_ws, size_t ws_size,
                              hipStream_t stream)
{
    const float* InStates = (const float*)d_in[0];
    const float* Psi0     = (const float*)d_in[1];
    const float* bias0    = (const float*)d_in[2];
    const float* Psi1     = (const float*)d_in[3];
    const float* bias1    = (const float*)d_in[4];
    const float* Psi2     = (const float*)d_in[5];
    const float* bias2    = (const float*)d_in[6];
    const float* wtVC     = (const float*)d_in[7];
    const float* ShellW   = (const float*)d_in[8];
    const float* gdiags   = (const float*)d_in[9];
    const int*   GnnPerms = (const int*)d_in[10];
    const int*   NNSites  = (const int*)d_in[11];
    const int*   S2Sh     = (const int*)d_in[12];

    float*  ws   = (float*)d_ws;
    float*  Avc  = ws + OFF_AVC;
    __bf16* U    = (__bf16*)(ws + OFF_U);
    __bf16* Ah0  = (__bf16*)(ws + OFF_AH0);
    __bf16* Al0  = (__bf16*)(ws + OFF_AL0);
    __bf16* Ah1  = (__bf16*)(ws + OFF_AH1);
    __bf16* Al1  = (__bf16*)(ws + OFF_AL1);
    float*  A2   = ws + OFF_A2;      // aliases Ah0 (dead when L2 runs)
    float*  PART = ws + OFF_PART;

    float* out = (float*)d_out;      // (64,3) f32

    hipMemsetAsync(Avc, 0, 39 * sizeof(float), stream);
    precompute_kernel<<<272, 256, 0, stream>>>(Psi0, Psi1, Psi2, wtVC, gdiags,
                                               GnnPerms, ws);

    // grid = B * (S/CT)/P = 64 * 16 = 1024 blocks for all layers
    // L0: f32 input, split-bf16 output
    layer_pipe<1, 8, 64, 32, 40, 8, 1, 4, 1><<<1024, 512, 0, stream>>>(
        InStates, nullptr, nullptr, U + UW0H, U + UW0L, bias0, NNSites,
        nullptr, Ah0, Al0);
    // L1: pre-split input, split-bf16 output
    layer_pipe<8, 8, 64, 128, 136, 8, 1, 4, 1><<<1024, 512, 0, stream>>>(
        nullptr, Ah0, Al0, U + UW1H, U + UW1L, bias1, NNSites,
        nullptr, Ah1, Al1);
    // L2: pre-split input, f32 (B,S) output
    layer_pipe<8, 1, 64, 128, 136, 4, 4, 4, 0><<<1024, 256, 0, stream>>>(
        nullptr, Ah1, Al1, U + UW2H, U + UW2L, bias2, NNSites,
        A2, nullptr, nullptr);

    reduce_a<<<BATCH * 16, 256, 0, stream>>>(A2, NNSites, S2Sh, ShellW, Avc, PART);
    reduce_b<<<1, 256, 0, stream>>>(PART, out);
}

// Round 11
// 395.522 us; speedup vs baseline: 1.2313x; 1.2313x over previous
//
#include <hip/hip_runtime.h>
#include <hip/hip_bf16.h>

// Problem constants (SymNetDP): B=64, S=4096, NGB=13, NG=48, DIM=3, NCH={8,8,1}
#define BATCH 64
#define SITES 4096
#define NGB 13
#define NGRP 48
#define SDIM 3

typedef __bf16 bf16x8 __attribute__((ext_vector_type(8)));
typedef float  f32x4  __attribute__((ext_vector_type(4)));

// ---------------------------------------------------------------------------
// Workspace layout (floats):
//   Avc  : 39 f32 (pad 64)              @ 0
//   U    : bf16 x 135168 (67584 f)      @ 64
//     W0H [384][32] | W0L | W1H [384][128] | W1L | W2H [48][128] | W2L
//     (bias folded at k=13 (W0) / k=104 (W1,W2); x carries 1.0 there)
//   A0   : (B,S,8) f32                  @ 67648
//   A1   : (B,S,8) f32                  @ 2164800
//   C    : [3][4096] f32                @ 4261952   (scatter matrix)
//   PART : [4096][3] f32                @ 4274240
// K-packing (NCIN=8): k = j*8 + c  (a site's 8 channels contiguous).
// ---------------------------------------------------------------------------
#define OFF_AVC  0
#define OFF_U    64
#define OFF_A0   67648
#define OFF_A1   2164800
#define OFF_C    4261952
#define OFF_PART 4274240
#define UW0H 0
#define UW0L 12288
#define UW1H 24576
#define UW1L 73728
#define UW2H 122880
#define UW2L 129024

__device__ __forceinline__ float softplus_f(float h) {
    return fmaxf(h, 0.f) + __logf(1.f + __expf(-fabsf(h)));
}

// ---------------------------------------------------------------------------
// Precompute: rotated weights, bf16 hi/lo split, [row=o*48+g][KPAD], with the
// BIAS placed at k=13 (W0) / k=104 (W1,W2). The standard hi/lo split puts
// bias_hi in Wh and bias_lo in Wl; with x_hi=1, x_lo=0 at that slot, the
// hi*hi and lo*hi MFMA terms reconstruct the f32 bias. Plus Avc (atomics).
// ---------------------------------------------------------------------------
__global__ __launch_bounds__(256) void precompute_kernel(
    const float* __restrict__ Psi0, const float* __restrict__ bias0,
    const float* __restrict__ Psi1, const float* __restrict__ bias1,
    const float* __restrict__ Psi2, const float* __restrict__ bias2,
    const float* __restrict__ wtVC,
    const float* __restrict__ gdiags, const int* __restrict__ perms,
    float* __restrict__ ws)
{
    float*  Avc = ws + OFF_AVC;
    __bf16* U   = (__bf16*)(ws + OFF_U);
    int t = blockIdx.x * 256 + threadIdx.x;
    if (t < 12288) {                       // W0: [384][32], k=j; bias at k=13
        int k = t & 31, row = t >> 5;
        int o = row / NGRP, g = row - o * NGRP;
        float w = 0.f;
        if (k < NGB)       w = Psi0[o * NGB + perms[g * NGB + k]];
        else if (k == NGB) w = bias0[o];
        __bf16 hi = (__bf16)w;
        U[UW0H + t] = hi;
        U[UW0L + t] = (__bf16)(w - (float)hi);
    } else if (t < 61440) {                // W1: [384][128], k=j*8+c; bias@104
        int u = t - 12288;
        int k = u & 127, row = u >> 7;
        int o = row / NGRP, g = row - o * NGRP;
        float w = 0.f;
        if (k < 104) { int j = k >> 3, c = k & 7;
                       w = Psi1[(o * 8 + c) * NGB + perms[g * NGB + j]]; }
        else if (k == 104) w = bias1[o];
        __bf16 hi = (__bf16)w;
        U[UW1H + u] = hi;
        U[UW1L + u] = (__bf16)(w - (float)hi);
    } else if (t < 67584) {                // W2: [48][128], k=j*8+c; bias@104
        int u = t - 61440;
        int k = u & 127, g = u >> 7;
        float w = 0.f;
        if (k < 104) { int j = k >> 3, c = k & 7;
                       w = Psi2[c * NGB + perms[g * NGB + j]]; }
        else if (k == 104) w = bias2[0];
        __bf16 hi = (__bf16)w;
        U[UW2H + u] = hi;
        U[UW2L + u] = (__bf16)(w - (float)hi);
    } else if (t < 67584 + 39 * NGRP) {    // Avc
        int t2 = t - 67584;
        int g = t2 % NGRP, u = t2 / NGRP;
        int d = u / NGB, n = u % NGB;
        const int row = g * SDIM + d;
        float s = 0.f;
        for (int k = 0; k < NGRP * SDIM; k++) {
            int g2 = k / SDIM, d2 = k - g2 * SDIM;
            float p = wtVC[d2 * NGB + perms[g2 * NGB + n]];
            s = fmaf(gdiags[row * (NGRP * SDIM) + k], p, s);
        }
        atomicAdd(&Avc[u], s * (1.f / 48.f));
    }
}

// ---------------------------------------------------------------------------
// Precompute C[d][t] = sum_{(n,s): NN[n,s]=t} Avc[d,n] * sw[shell[s]]
// (scatter-atomic; C zeroed by memset). Runs after precompute_kernel.
// ---------------------------------------------------------------------------
__global__ __launch_bounds__(256) void precompute_C(
    const int* __restrict__ NN, const int* __restrict__ s2sh,
    const float* __restrict__ sw, const float* __restrict__ ws_avc,
    float* __restrict__ C)
{
    int e = blockIdx.x * 256 + threadIdx.x;
    if (e < NGB * SITES) {
        int n = e >> 12, s = e & (SITES - 1);
        int t = NN[n * SITES + s];
        float w = sw[s2sh[s]];
        atomicAdd(&C[t],            ws_avc[n] * w);
        atomicAdd(&C[SITES + t],    ws_avc[NGB + n] * w);
        atomicAdd(&C[2 * SITES + t], ws_avc[2 * NGB + n] * w);
    }
}

// ---------------------------------------------------------------------------
// MFMA gconv layer (bf16x3 split), round-9 proven structure.
// Bias comes in through the padded K slot (x=1 there) -> no epilogue add.
// ---------------------------------------------------------------------------
template<int NCIN, int NCTOT, int CT, int KPAD, int KSTR, int NWAVES, int NWN>
__global__ __launch_bounds__(NWAVES * 64) void layer_mfma(
    const float* __restrict__ prev,   // (B,S) if NCIN==1 else (B,S,8)
    const __bf16* __restrict__ Wh,    // [NCTOT*48][KPAD]
    const __bf16* __restrict__ Wl,
    const int*   __restrict__ NN,     // (13, S)
    float* __restrict__ out)          // (B,S,NCTOT) channel-last
{
    constexpr int NTHR   = NWAVES * 64;
    constexpr int K      = NCIN * NGB;
    constexpr int M      = NCTOT * NGRP;
    constexpr int MTILES = M / 16, NTILES = CT / 16;
    constexpr int NWM    = NWAVES / NWN;
    constexpr int MT_W   = MTILES / NWM, NT_W = NTILES / NWN;
    constexpr int KT     = KPAD / 32;

    static_assert(MT_W * 16 == NGRP, "wave covers exactly one o");
    static_assert(NWM * MT_W == MTILES && NWN * NT_W == NTILES, "");
    static_assert((KPAD & 31) == 0 && (KSTR & 7) == 0, "");

    __shared__ __align__(16) __bf16 xh_lds[CT * KSTR];
    __shared__ __align__(16) __bf16 xl_lds[CT * KSTR];

    const int tid  = threadIdx.x;
    const int wave = tid >> 6, lane = tid & 63;
    const int m16  = lane & 15, quad = lane >> 4;

    const int b  = blockIdx.x / (SITES / CT);
    const int s0 = (blockIdx.x % (SITES / CT)) * CT;

    // --- gather + split X into LDS ------------------------------------------
    if constexpr (NCIN == 1) {
        for (int site = tid; site < NGB * CT; site += NTHR) {
            int j = site / CT, col = site % CT;
            int nn = NN[j * SITES + s0 + col];
            float v = prev[(size_t)b * SITES + nn];
            __bf16 hi = (__bf16)v;
            xh_lds[col * KSTR + j] = hi;
            xl_lds[col * KSTR + j] = (__bf16)(v - (float)hi);
        }
        for (int e = tid; e < CT * (KPAD - K); e += NTHR) {
            int col = e / (KPAD - K), p = e % (KPAD - K);
            xh_lds[col * KSTR + K + p] = (p == 0) ? (__bf16)1.f : (__bf16)0.f;
            xl_lds[col * KSTR + K + p] = (__bf16)0.f;
        }
    } else {
        for (int site = tid; site < NGB * CT; site += NTHR) {
            int j = site / CT, col = site % CT;
            int nn = NN[j * SITES + s0 + col];
            const float4* p4 = (const float4*)(prev + ((size_t)(b * SITES + nn)) * 8);
            float4 u0 = p4[0], u1 = p4[1];
            float v[8] = {u0.x, u0.y, u0.z, u0.w, u1.x, u1.y, u1.z, u1.w};
            bf16x8 hv, lv;
#pragma unroll
            for (int c = 0; c < 8; c++) {
                __bf16 hi = (__bf16)v[c];
                hv[c] = hi;
                lv[c] = (__bf16)(v[c] - (float)hi);
            }
            *(bf16x8*)(xh_lds + col * KSTR + j * 8) = hv;
            *(bf16x8*)(xl_lds + col * KSTR + j * 8) = lv;
        }
        // pad k in [104,128): k=104 carries x=1.0 (bias slot), rest zero
        bf16x8 z8 = {};
        bf16x8 one8 = {};
        one8[0] = (__bf16)1.f;
        for (int e = tid; e < CT * 3; e += NTHR) {
            int col = e % CT, z = e / CT;
            *(bf16x8*)(xh_lds + col * KSTR + K + z * 8) = (z == 0) ? one8 : z8;
            *(bf16x8*)(xl_lds + col * KSTR + K + z * 8) = z8;
        }
    }
    __syncthreads();

    const int wave_mt0 = (wave / NWN) * MT_W;
    const int wave_nt0 = (wave % NWN) * NT_W;
    const int o_g      = (wave_mt0 * 16) / NGRP;

    f32x4 acc[MT_W][NT_W];
#pragma unroll
    for (int mt = 0; mt < MT_W; mt++)
#pragma unroll
        for (int nt = 0; nt < NT_W; nt++) acc[mt][nt] = (f32x4){0.f, 0.f, 0.f, 0.f};

    // --- K loop (full unroll; hi*hi + lo*hi + hi*lo) ------------------------
#pragma unroll
    for (int kt = 0; kt < KT; kt++) {
        const int koff = kt * 32 + quad * 8;
        bf16x8 ah[MT_W], al[MT_W], bh[NT_W], bl[NT_W];
#pragma unroll
        for (int mt = 0; mt < MT_W; mt++) {
            int row = (wave_mt0 + mt) * 16 + m16;
            ah[mt] = *(const bf16x8*)(Wh + (size_t)row * KPAD + koff);
            al[mt] = *(const bf16x8*)(Wl + (size_t)row * KPAD + koff);
        }
#pragma unroll
        for (int nt = 0; nt < NT_W; nt++) {
            int cbase = ((wave_nt0 + nt) * 16 + m16) * KSTR + koff;
            bh[nt] = *(const bf16x8*)(xh_lds + cbase);
            bl[nt] = *(const bf16x8*)(xl_lds + cbase);
        }
#pragma unroll
        for (int mt = 0; mt < MT_W; mt++)
#pragma unroll
            for (int nt = 0; nt < NT_W; nt++) {
                acc[mt][nt] = __builtin_amdgcn_mfma_f32_16x16x32_bf16(
                    ah[mt], bh[nt], acc[mt][nt], 0, 0, 0);
                acc[mt][nt] = __builtin_amdgcn_mfma_f32_16x16x32_bf16(
                    al[mt], bh[nt], acc[mt][nt], 0, 0, 0);
                acc[mt][nt] = __builtin_amdgcn_mfma_f32_16x16x32_bf16(
                    ah[mt], bl[nt], acc[mt][nt], 0, 0, 0);
            }
    }

    // --- epilogue: softplus + group mean (bias already inside acc) ----------
#pragma unroll
    for (int nt = 0; nt < NT_W; nt++) {
        float s = 0.f;
#pragma unroll
        for (int mt = 0; mt < MT_W; mt++)
#pragma unroll
            for (int r = 0; r < 4; r++)
                s += softplus_f(acc[mt][nt][r]);
        s += __shfl_xor(s, 16);
        s += __shfl_xor(s, 32);
        if (quad == 0)
            out[((size_t)(b * SITES + s0 + (wave_nt0 + nt) * 16 + m16)) * NCTOT + o_g]
                = s * (1.f / 48.f);
    }
}

// ---------------------------------------------------------------------------
// Fused layer-2 + vector-channel reduction.
// 512 thr = 8 waves; waves (nt = wave&3) own col-tiles, kh = wave>>2 splits
// the K range in half (2 kt each). Partial accs combined through LDS, then
// softplus + group mean + dot with C[d][site] -> 3 per-block partials.
// ---------------------------------------------------------------------------
__global__ __launch_bounds__(512) void layer2_fused(
    const float* __restrict__ prev,   // A1 (B,S,8)
    const __bf16* __restrict__ Wh,    // [48][128] (bias at k=104)
    const __bf16* __restrict__ Wl,
    const int* __restrict__ NN,
    const float* __restrict__ C,      // [3][4096]
    float* __restrict__ part)         // [B*64][3]
{
    constexpr int CT = 64, KPAD = 128, KSTR = 136, K = 104;

    __shared__ __align__(16) __bf16 xh_lds[CT * KSTR];
    __shared__ __align__(16) __bf16 xl_lds[CT * KSTR];
    __shared__ float wsum[4][3];

    const int tid  = threadIdx.x;
    const int wave = tid >> 6, lane = tid & 63;
    const int m16  = lane & 15, quad = lane >> 4;

    const int b     = blockIdx.x >> 6;        // 64 chunks per b
    const int chunk = blockIdx.x & 63;
    const int s0    = chunk * CT;
    const size_t bS = (size_t)b * SITES;

    // --- gather + split (identical pattern to layer_mfma NCIN==8) -----------
    for (int site = tid; site < NGB * CT; site += 512) {
        int j = site / CT, col = site % CT;
        int nn = NN[j * SITES + s0 + col];
        const float4* p4 = (const float4*)(prev + (bS + nn) * 8);
        float4 u0 = p4[0], u1 = p4[1];
        float v[8] = {u0.x, u0.y, u0.z, u0.w, u1.x, u1.y, u1.z, u1.w};
        bf16x8 hv, lv;
#pragma unroll
        for (int c = 0; c < 8; c++) {
            __bf16 hi = (__bf16)v[c];
            hv[c] = hi;
            lv[c] = (__bf16)(v[c] - (float)hi);
        }
        *(bf16x8*)(xh_lds + col * KSTR + j * 8) = hv;
        *(bf16x8*)(xl_lds + col * KSTR + j * 8) = lv;
    }
    {
        bf16x8 z8 = {};
        bf16x8 one8 = {};
        one8[0] = (__bf16)1.f;
        for (int e = tid; e < CT * 3; e += 512) {
            int col = e % CT, z = e / CT;
            *(bf16x8*)(xh_lds + col * KSTR + K + z * 8) = (z == 0) ? one8 : z8;
            *(bf16x8*)(xl_lds + col * KSTR + K + z * 8) = z8;
        }
    }
    __syncthreads();

    const int nt = wave & 3, kh = wave >> 2;

    f32x4 acc[3];
#pragma unroll
    for (int mt = 0; mt < 3; mt++) acc[mt] = (f32x4){0.f, 0.f, 0.f, 0.f};

#pragma unroll
    for (int kk = 0; kk < 2; kk++) {
        const int koff = (kh * 2 + kk) * 32 + quad * 8;
        bf16x8 ah[3], al[3];
#pragma unroll
        for (int mt = 0; mt < 3; mt++) {
            int row = mt * 16 + m16;
            ah[mt] = *(const bf16x8*)(Wh + (size_t)row * KPAD + koff);
            al[mt] = *(const bf16x8*)(Wl + (size_t)row * KPAD + koff);
        }
        int cbase = (nt * 16 + m16) * KSTR + koff;
        bf16x8 bh = *(const bf16x8*)(xh_lds + cbase);
        bf16x8 bl = *(const bf16x8*)(xl_lds + cbase);
#pragma unroll
        for (int mt = 0; mt < 3; mt++) {
            acc[mt] = __builtin_amdgcn_mfma_f32_16x16x32_bf16(ah[mt], bh, acc[mt], 0, 0, 0);
            acc[mt] = __builtin_amdgcn_mfma_f32_16x16x32_bf16(al[mt], bh, acc[mt], 0, 0, 0);
            acc[mt] = __builtin_amdgcn_mfma_f32_16x16x32_bf16(ah[mt], bl, acc[mt], 0, 0, 0);
        }
    }
    __syncthreads();                      // all K-loop LDS reads done

    // --- combine K halves via LDS (reuse xh_lds as f32 scratch) -------------
    float* hpart = (float*)xh_lds;        // [nt][row(48)][col(16)]
    if (kh == 1) {
#pragma unroll
        for (int mt = 0; mt < 3; mt++)
#pragma unroll
            for (int r = 0; r < 4; r++)
                hpart[nt * 768 + (mt * 16 + quad * 4 + r) * 16 + m16] = acc[mt][r];
    }
    __syncthreads();

    if (kh == 0) {
        float s = 0.f;
#pragma unroll
        for (int mt = 0; mt < 3; mt++)
#pragma unroll
            for (int r = 0; r < 4; r++)
                s += softplus_f(acc[mt][r] +
                                hpart[nt * 768 + (mt * 16 + quad * 4 + r) * 16 + m16]);
        // sum over the 4 quads' row-subsets -> full 48-row sum per col m16
        s += __shfl_xor(s, 16);
        s += __shfl_xor(s, 32);
        float a2 = s * (1.f / 48.f);
        int site = s0 + nt * 16 + m16;
        float y0 = a2 * C[site];
        float y1 = a2 * C[SITES + site];
        float y2 = a2 * C[2 * SITES + site];
        // sum over the 16 cols (identical copies across quads)
#pragma unroll
        for (int d = 1; d <= 8; d <<= 1) {
            y0 += __shfl_xor(y0, d);
            y1 += __shfl_xor(y1, d);
            y2 += __shfl_xor(y2, d);
        }
        if (lane == 0) { wsum[nt][0] = y0; wsum[nt][1] = y1; wsum[nt][2] = y2; }
    }
    __syncthreads();
    if (tid < 3) {
        float s = wsum[0][tid] + wsum[1][tid] + wsum[2][tid] + wsum[3][tid];
        part[blockIdx.x * 3 + tid] = s;
    }
}

// ---------------------------------------------------------------------------
// Final deterministic combine: out[b,d] = (1/S) * sum_{chunk} part[b,chunk,d]
// ---------------------------------------------------------------------------
__global__ __launch_bounds__(256) void reduce_b(
    const float* __restrict__ part, float* __restrict__ out)
{
    int t = threadIdx.x;
    if (t < BATCH * 3) {
        int b = t / 3, d = t - b * 3;
        float s = 0.f;
        for (int c = 0; c < 64; c++) s += part[(b * 64 + c) * 3 + d];
        out[t] = s * (1.f / (float)SITES);
    }
}

// ---------------------------------------------------------------------------
extern "C" void kernel_launch(void* const* d_in, const int* in_sizes, int n_in,
                              void* d_out, int out_size, void* d_ws, size_t ws_size,
                              hipStream_t stream)
{
    const float* InStates = (const float*)d_in[0];
    const float* Psi0     = (const float*)d_in[1];
    const float* bias0    = (const float*)d_in[2];
    const float* Psi1     = (const float*)d_in[3];
    const float* bias1    = (const float*)d_in[4];
    const float* Psi2     = (const float*)d_in[5];
    const float* bias2    = (const float*)d_in[6];
    const float* wtVC     = (const float*)d_in[7];
    const float* ShellW   = (const float*)d_in[8];
    const float* gdiags   = (const float*)d_in[9];
    const int*   GnnPerms = (const int*)d_in[10];
    const int*   NNSites  = (const int*)d_in[11];
    const int*   S2Sh     = (const int*)d_in[12];

    float*  ws   = (float*)d_ws;
    float*  Avc  = ws + OFF_AVC;
    __bf16* U    = (__bf16*)(ws + OFF_U);
    float*  A0   = ws + OFF_A0;      // (B,S,8) channel-last f32
    float*  A1   = ws + OFF_A1;      // (B,S,8) channel-last f32
    float*  C    = ws + OFF_C;       // [3][4096]
    float*  PART = ws + OFF_PART;    // [4096][3]

    float* out = (float*)d_out;      // (64,3) f32

    hipMemsetAsync(Avc, 0, 39 * sizeof(float), stream);
    hipMemsetAsync(C, 0, 3 * SITES * sizeof(float), stream);

    precompute_kernel<<<272, 256, 0, stream>>>(Psi0, bias0, Psi1, bias1,
                                               Psi2, bias2, wtVC, gdiags,
                                               GnnPerms, ws);
    precompute_C<<<208, 256, 0, stream>>>(NNSites, S2Sh, ShellW, Avc, C);

    // L0: K=13 pad 32 (bias at k=13), KSTR=40
    layer_mfma<1, 8, 64, 32, 40, 8, 1><<<BATCH * (SITES / 64), 512, 0, stream>>>(
        InStates, U + UW0H, U + UW0L, NNSites, A0);
    // L1: K=104 pad 128 (bias at k=104), KSTR=136
    layer_mfma<8, 8, 64, 128, 136, 8, 1><<<BATCH * (SITES / 64), 512, 0, stream>>>(
        A0, U + UW1H, U + UW1L, NNSites, A1);
    // L2 fused with vector-channel reduction (8 waves, K-split)
    layer2_fused<<<BATCH * 64, 512, 0, stream>>>(
        A1, U + UW2H, U + UW2L, NNSites, C, PART);

    reduce_b<<<1, 256, 0, stream>>>(PART, out);
}

// Round 12
// 389.218 us; speedup vs baseline: 1.2512x; 1.0162x over previous
//
#include <hip/hip_runtime.h>
#include <hip/hip_bf16.h>

// Problem constants (SymNetDP): B=64, S=4096, NGB=13, NG=48, DIM=3, NCH={8,8,1}
#define BATCH 64
#define SITES 4096
#define NGB 13
#define NGRP 48
#define SDIM 3

typedef __bf16 bf16x8 __attribute__((ext_vector_type(8)));
typedef float  f32x4  __attribute__((ext_vector_type(4)));

// ---------------------------------------------------------------------------
// Workspace layout (floats):
//   Avc  : 39 f32 (pad 64)              @ 0
//   U    : bf16 x 135168 (67584 f)      @ 64
//     W0H [384][32] | W0L | W1H [384][128] | W1L | W2H [48][128] | W2L
//     (bias folded at k=13 (W0) / k=104 (W1,W2); x carries 1.0 there)
//   A0   : (B,S,8) f32                  @ 67648
//   A1   : (B,S,8) f32                  @ 2164800
//   C    : [3][4096] f32                @ 4261952   (scatter matrix)
//   PART : [1024][3] f32                @ 4274240
// K-packing (NCIN=8): k = j*8 + c  (a site's 8 channels contiguous).
// ---------------------------------------------------------------------------
#define OFF_AVC  0
#define OFF_U    64
#define OFF_A0   67648
#define OFF_A1   2164800
#define OFF_C    4261952
#define OFF_PART 4274240
#define UW0H 0
#define UW0L 12288
#define UW1H 24576
#define UW1L 73728
#define UW2H 122880
#define UW2L 129024

__device__ __forceinline__ float softplus_f(float h) {
    return fmaxf(h, 0.f) + __logf(1.f + __expf(-fabsf(h)));
}

// ---------------------------------------------------------------------------
// Precompute: rotated weights, bf16 hi/lo split, [row=o*48+g][KPAD], with the
// BIAS placed at k=13 (W0) / k=104 (W1,W2); x carries 1.0 in that slot.
// Plus Avc (atomics, zeroed by memset).
// ---------------------------------------------------------------------------
__global__ __launch_bounds__(256) void precompute_kernel(
    const float* __restrict__ Psi0, const float* __restrict__ bias0,
    const float* __restrict__ Psi1, const float* __restrict__ bias1,
    const float* __restrict__ Psi2, const float* __restrict__ bias2,
    const float* __restrict__ wtVC,
    const float* __restrict__ gdiags, const int* __restrict__ perms,
    float* __restrict__ ws)
{
    float*  Avc = ws + OFF_AVC;
    __bf16* U   = (__bf16*)(ws + OFF_U);
    int t = blockIdx.x * 256 + threadIdx.x;
    if (t < 12288) {                       // W0: [384][32], k=j; bias at k=13
        int k = t & 31, row = t >> 5;
        int o = row / NGRP, g = row - o * NGRP;
        float w = 0.f;
        if (k < NGB)       w = Psi0[o * NGB + perms[g * NGB + k]];
        else if (k == NGB) w = bias0[o];
        __bf16 hi = (__bf16)w;
        U[UW0H + t] = hi;
        U[UW0L + t] = (__bf16)(w - (float)hi);
    } else if (t < 61440) {                // W1: [384][128], k=j*8+c; bias@104
        int u = t - 12288;
        int k = u & 127, row = u >> 7;
        int o = row / NGRP, g = row - o * NGRP;
        float w = 0.f;
        if (k < 104) { int j = k >> 3, c = k & 7;
                       w = Psi1[(o * 8 + c) * NGB + perms[g * NGB + j]]; }
        else if (k == 104) w = bias1[o];
        __bf16 hi = (__bf16)w;
        U[UW1H + u] = hi;
        U[UW1L + u] = (__bf16)(w - (float)hi);
    } else if (t < 67584) {                // W2: [48][128], k=j*8+c; bias@104
        int u = t - 61440;
        int k = u & 127, g = u >> 7;
        float w = 0.f;
        if (k < 104) { int j = k >> 3, c = k & 7;
                       w = Psi2[c * NGB + perms[g * NGB + j]]; }
        else if (k == 104) w = bias2[0];
        __bf16 hi = (__bf16)w;
        U[UW2H + u] = hi;
        U[UW2L + u] = (__bf16)(w - (float)hi);
    } else if (t < 67584 + 39 * NGRP) {    // Avc
        int t2 = t - 67584;
        int g = t2 % NGRP, u = t2 / NGRP;
        int d = u / NGB, n = u % NGB;
        const int row = g * SDIM + d;
        float s = 0.f;
        for (int k = 0; k < NGRP * SDIM; k++) {
            int g2 = k / SDIM, d2 = k - g2 * SDIM;
            float p = wtVC[d2 * NGB + perms[g2 * NGB + n]];
            s = fmaf(gdiags[row * (NGRP * SDIM) + k], p, s);
        }
        atomicAdd(&Avc[u], s * (1.f / 48.f));
    }
}

// ---------------------------------------------------------------------------
// Precompute C[d][t] = sum_{(n,s): NN[n,s]=t} Avc[d,n] * sw[shell[s]]
// ---------------------------------------------------------------------------
__global__ __launch_bounds__(256) void precompute_C(
    const int* __restrict__ NN, const int* __restrict__ s2sh,
    const float* __restrict__ sw, const float* __restrict__ ws_avc,
    float* __restrict__ C)
{
    int e = blockIdx.x * 256 + threadIdx.x;
    if (e < NGB * SITES) {
        int n = e >> 12, s = e & (SITES - 1);
        int t = NN[n * SITES + s];
        float w = sw[s2sh[s]];
        atomicAdd(&C[t],             ws_avc[n] * w);
        atomicAdd(&C[SITES + t],     ws_avc[NGB + n] * w);
        atomicAdd(&C[2 * SITES + t], ws_avc[2 * NGB + n] * w);
    }
}

// ---------------------------------------------------------------------------
// Pipelined MFMA gconv layer (bf16x3 split), v12.
// 256 threads = 4 waves. Block processes P chunks of CT columns; gathers for
// chunk p+1 are issued into REGISTERS (f32) before chunk p's K-loop, then
// committed (bf16-split) to the single LDS buffer between two barriers.
// NWM row-split x NWN col-split waves; MT_W multiple of 3 (o = 3 tiles).
// FUSE=1: layer-2 epilogue dots softplus-mean with C and accumulates per-wave
// partials across chunks -> part[block][3] (no A2 array, no reduce_a).
// ---------------------------------------------------------------------------
template<int NCIN, int NCTOT, int CT, int KPAD, int KSTR, int NWM, int NWN,
         int P, int FUSE>
__global__ __launch_bounds__(256) void layer_pipe(
    const float*  __restrict__ prev,  // (B,S) if NCIN==1 else (B,S,8) f32
    const __bf16* __restrict__ Wh,    // [NCTOT*48][KPAD]
    const __bf16* __restrict__ Wl,
    const int*    __restrict__ NN,    // (13, S)
    const float*  __restrict__ C,     // FUSE: [3][4096]
    float* __restrict__ out,          // FUSE==0: (B,S,NCTOT) f32
    float* __restrict__ part)         // FUSE==1: [grid][3]
{
    constexpr int K      = NCIN * NGB;
    constexpr int MTILES = NCTOT * 3;
    constexpr int NTILES = CT / 16;
    constexpr int MT_W   = MTILES / NWM;
    constexpr int NT_W   = NTILES / NWN;
    constexpr int KT     = KPAD / 32;
    constexpr int OPW    = MT_W / 3;          // o's per wave
    constexpr int NSITE  = NGB * CT;
    constexpr int NSL    = (NSITE + 255) / 256;
    constexpr int QPB    = (SITES / CT) / P;

    static_assert(NWM * NWN == 4, "4 waves");
    static_assert(MT_W * NWM == MTILES && NT_W * NWN == NTILES, "");
    static_assert(MT_W % 3 == 0, "wave rows = whole o's");
    static_assert((KPAD & 31) == 0, "");

    __shared__ __align__(16) __bf16 xh_lds[CT * KSTR];
    __shared__ __align__(16) __bf16 xl_lds[CT * KSTR];
    __shared__ float wsum[4][3];

    const int tid  = threadIdx.x;
    const int wave = tid >> 6, lane = tid & 63;
    const int m16  = lane & 15, quad = lane >> 4;

    const int b     = blockIdx.x / QPB;
    const int qq    = blockIdx.x % QPB;
    const int sbase = qq * (P * CT);
    const size_t bS = (size_t)b * SITES;

    const int wave_mt0 = (wave / NWN) * MT_W;
    const int wave_nt0 = (wave % NWN) * NT_W;

    // --- pad region [K, KPAD): bias slot gets x=1.0 (hi), rest zero ---------
    if constexpr (NCIN == 8) {
        bf16x8 z8 = {};
        bf16x8 one8 = {};
        one8[0] = (__bf16)1.f;
        for (int e = tid; e < CT * 3; e += 256) {
            int col = e % CT, z = e / CT;
            *(bf16x8*)(xh_lds + col * KSTR + K + z * 8) = (z == 0) ? one8 : z8;
            *(bf16x8*)(xl_lds + col * KSTR + K + z * 8) = z8;
        }
    } else {
        for (int e = tid; e < CT * (KPAD - K); e += 256) {
            int col = e / (KPAD - K), p = e % (KPAD - K);
            xh_lds[col * KSTR + K + p] = (p == 0) ? (__bf16)1.f : (__bf16)0.f;
            xl_lds[col * KSTR + K + p] = (__bf16)0.f;
        }
    }

    // --- register staging state ---------------------------------------------
    float4 fA[NSL], fB[NSL];
    float  v1[NSL];

    auto gather = [&](int pp) {
        const int s0_ = sbase + pp * CT;
#pragma unroll
        for (int i = 0; i < NSL; i++) {
            int site = tid + i * 256;
            if (site < NSITE) {
                int j = site / CT, col = site % CT;
                int nn = NN[j * SITES + s0_ + col];
                if constexpr (NCIN == 1) {
                    v1[i] = prev[bS + nn];
                } else {
                    const float4* p4 = (const float4*)(prev + (bS + nn) * 8);
                    fA[i] = p4[0];
                    fB[i] = p4[1];
                }
            }
        }
    };

    auto commit = [&]() {
#pragma unroll
        for (int i = 0; i < NSL; i++) {
            int site = tid + i * 256;
            if (site < NSITE) {
                int j = site / CT, col = site % CT;
                if constexpr (NCIN == 1) {
                    __bf16 hi = (__bf16)v1[i];
                    xh_lds[col * KSTR + j] = hi;
                    xl_lds[col * KSTR + j] = (__bf16)(v1[i] - (float)hi);
                } else {
                    float v[8] = {fA[i].x, fA[i].y, fA[i].z, fA[i].w,
                                  fB[i].x, fB[i].y, fB[i].z, fB[i].w};
                    bf16x8 hv, lv;
#pragma unroll
                    for (int c = 0; c < 8; c++) {
                        __bf16 hi = (__bf16)v[c];
                        hv[c] = hi;
                        lv[c] = (__bf16)(v[c] - (float)hi);
                    }
                    *(bf16x8*)(xh_lds + col * KSTR + j * 8) = hv;
                    *(bf16x8*)(xl_lds + col * KSTR + j * 8) = lv;
                }
            }
        }
    };

    gather(0);

    float y0 = 0.f, y1 = 0.f, y2 = 0.f;   // FUSE accumulators

#pragma unroll 1
    for (int p = 0; p < P; p++) {
        __syncthreads();                  // prior chunk's LDS reads done
        commit();
        __syncthreads();
        if (p + 1 < P) gather(p + 1);     // issue next gathers (hidden)

        const int s0_ = sbase + p * CT;

        f32x4 acc[MT_W][NT_W];
#pragma unroll
        for (int mt = 0; mt < MT_W; mt++)
#pragma unroll
            for (int nt = 0; nt < NT_W; nt++)
                acc[mt][nt] = (f32x4){0.f, 0.f, 0.f, 0.f};

        // K loop: hi*hi + lo*hi + hi*lo per (tile, k32)
#pragma unroll
        for (int kt = 0; kt < KT; kt++) {
            const int koff = kt * 32 + quad * 8;
            bf16x8 ah[MT_W], al[MT_W], bh[NT_W], bl[NT_W];
#pragma unroll
            for (int mt = 0; mt < MT_W; mt++) {
                int row = (wave_mt0 + mt) * 16 + m16;
                ah[mt] = *(const bf16x8*)(Wh + (size_t)row * KPAD + koff);
                al[mt] = *(const bf16x8*)(Wl + (size_t)row * KPAD + koff);
            }
#pragma unroll
            for (int nt = 0; nt < NT_W; nt++) {
                int cb = ((wave_nt0 + nt) * 16 + m16) * KSTR + koff;
                bh[nt] = *(const bf16x8*)(xh_lds + cb);
                bl[nt] = *(const bf16x8*)(xl_lds + cb);
            }
#pragma unroll
            for (int mt = 0; mt < MT_W; mt++)
#pragma unroll
                for (int nt = 0; nt < NT_W; nt++) {
                    acc[mt][nt] = __builtin_amdgcn_mfma_f32_16x16x32_bf16(
                        ah[mt], bh[nt], acc[mt][nt], 0, 0, 0);
                    acc[mt][nt] = __builtin_amdgcn_mfma_f32_16x16x32_bf16(
                        al[mt], bh[nt], acc[mt][nt], 0, 0, 0);
                    acc[mt][nt] = __builtin_amdgcn_mfma_f32_16x16x32_bf16(
                        ah[mt], bl[nt], acc[mt][nt], 0, 0, 0);
                }
        }

        // --- epilogue ------------------------------------------------------
        if constexpr (FUSE == 0) {
#pragma unroll
            for (int op = 0; op < OPW; op++) {
                const int o_g = wave_mt0 / 3 + op;
#pragma unroll
                for (int nt = 0; nt < NT_W; nt++) {
                    float s = 0.f;
#pragma unroll
                    for (int m = 0; m < 3; m++)
#pragma unroll
                        for (int r = 0; r < 4; r++)
                            s += softplus_f(acc[op * 3 + m][nt][r]);
                    s += __shfl_xor(s, 16);
                    s += __shfl_xor(s, 32);
                    if (quad == 0)
                        out[(bS + s0_ + (wave_nt0 + nt) * 16 + m16) * NCTOT + o_g]
                            = s * (1.f / 48.f);
                }
            }
        } else {
            float s = 0.f;
#pragma unroll
            for (int m = 0; m < 3; m++)
#pragma unroll
                for (int r = 0; r < 4; r++)
                    s += softplus_f(acc[m][0][r]);
            s += __shfl_xor(s, 16);
            s += __shfl_xor(s, 32);
            float a2 = s * (1.f / 48.f);
            int site = s0_ + wave_nt0 * 16 + m16;
            y0 = fmaf(a2, C[site],             y0);
            y1 = fmaf(a2, C[SITES + site],     y1);
            y2 = fmaf(a2, C[2 * SITES + site], y2);
        }
    }

    if constexpr (FUSE) {
        // reduce over the 16 lanes of each 16-group (quads hold copies)
#pragma unroll
        for (int d = 1; d <= 8; d <<= 1) {
            y0 += __shfl_xor(y0, d);
            y1 += __shfl_xor(y1, d);
            y2 += __shfl_xor(y2, d);
        }
        if (lane == 0) { wsum[wave][0] = y0; wsum[wave][1] = y1; wsum[wave][2] = y2; }
        __syncthreads();
        if (tid < 3)
            part[blockIdx.x * 3 + tid] =
                wsum[0][tid] + wsum[1][tid] + wsum[2][tid] + wsum[3][tid];
    }
}

// ---------------------------------------------------------------------------
// Final deterministic combine: out[b,d] = (1/S) * sum_{16 chunks} part
// ---------------------------------------------------------------------------
__global__ __launch_bounds__(256) void reduce_b(
    const float* __restrict__ part, float* __restrict__ out)
{
    int t = threadIdx.x;
    if (t < BATCH * 3) {
        int b = t / 3, d = t - b * 3;
        float s = 0.f;
        for (int c = 0; c < 16; c++) s += part[(b * 16 + c) * 3 + d];
        out[t] = s * (1.f / (float)SITES);
    }
}

// ---------------------------------------------------------------------------
extern "C" void kernel_launch(void* const* d_in, const int* in_sizes, int n_in,
                              void* d_out, int out_size, void* d_ws, size_t ws_size,
                              hipStream_t stream)
{
    const float* InStates = (const float*)d_in[0];
    const float* Psi0     = (const float*)d_in[1];
    const float* bias0    = (const float*)d_in[2];
    const float* Psi1     = (const float*)d_in[3];
    const float* bias1    = (const float*)d_in[4];
    const float* Psi2     = (const float*)d_in[5];
    const float* bias2    = (const float*)d_in[6];
    const float* wtVC     = (const float*)d_in[7];
    const float* ShellW   = (const float*)d_in[8];
    const float* gdiags   = (const float*)d_in[9];
    const int*   GnnPerms = (const int*)d_in[10];
    const int*   NNSites  = (const int*)d_in[11];
    const int*   S2Sh     = (const int*)d_in[12];

    float*  ws   = (float*)d_ws;
    float*  Avc  = ws + OFF_AVC;
    __bf16* U    = (__bf16*)(ws + OFF_U);
    float*  A0   = ws + OFF_A0;      // (B,S,8) channel-last f32
    float*  A1   = ws + OFF_A1;      // (B,S,8) channel-last f32
    float*  C    = ws + OFF_C;       // [3][4096]
    float*  PART = ws + OFF_PART;    // [1024][3]

    float* out = (float*)d_out;      // (64,3) f32

    hipMemsetAsync(Avc, 0, 39 * sizeof(float), stream);
    hipMemsetAsync(C, 0, 3 * SITES * sizeof(float), stream);

    precompute_kernel<<<272, 256, 0, stream>>>(Psi0, bias0, Psi1, bias1,
                                               Psi2, bias2, wtVC, gdiags,
                                               GnnPerms, ws);
    precompute_C<<<208, 256, 0, stream>>>(NNSites, S2Sh, ShellW, Avc, C);

    // L0: K=13 pad 32 (bias@13), CT=32, NWM=4 (2 o/wave), P=8 -> grid 1024
    layer_pipe<1, 8, 32, 32, 40, 4, 1, 8, 0><<<1024, 256, 0, stream>>>(
        InStates, U + UW0H, U + UW0L, NNSites, nullptr, A0, nullptr);
    // L1: K=104 pad 128 (bias@104), CT=32, NWM=4, P=8 -> grid 1024
    layer_pipe<8, 8, 32, 128, 136, 4, 1, 8, 0><<<1024, 256, 0, stream>>>(
        A0, U + UW1H, U + UW1L, NNSites, nullptr, A1, nullptr);
    // L2 fused with vector-channel reduction: CT=64, NWN=4, P=4 -> grid 1024
    layer_pipe<8, 1, 64, 128, 136, 1, 4, 4, 1><<<1024, 256, 0, stream>>>(
        A1, U + UW2H, U + UW2L, NNSites, C, nullptr, PART);

    reduce_b<<<1, 256, 0, stream>>>(PART, out);
}